// Round 6
// baseline (453.748 us; speedup 1.0000x reference)
//
#include <hip/hip_runtime.h>
#include <hip/hip_bf16.h>

// Problem constants
constexpr int B_   = 32;
constexpr int CIN  = 64;
constexpr int HIN  = 128;
constexpr int WIN  = 128;
constexpr int COUT = 128;
constexpr int HO   = 126;
constexpr int WO   = 126;
constexpr int HP   = 63;
constexpr int WP   = 63;
constexpr int NG   = 8;
constexpr float EPS = 1e-5f;

typedef _Float16 f16x8 __attribute__((ext_vector_type(8)));
typedef _Float16 f16x2 __attribute__((ext_vector_type(2)));
typedef float    f32x16 __attribute__((ext_vector_type(16)));

// ws layout (bytes):
//   stats @ 0        : 512 floats (pad to 4096)
//   Wh    @ 4096     : 9*8*128*8 f16 = 147456 (chunk-arranged)  (ends 151552)
//   xh    @ 151552   : 32*128*128*64 f16 = 64 MB NHWC           (ends 67260416; +4KB slack)
//   yp    @ 67264512 : 32*128*63*64 f16 = 33 MB (padded wp-stride 64)

// ---------- Prep: W (OIHW fp32) -> Wh[kk][t*2+q][co][8] f16 ----------
// B asm loads: lane(cl,q) reads byte kk*16384 + t*4096 + nt*512 + q*2048 + (ni*64+cl)*16
// -> per-instr two 512B contiguous segments (coalesced), uniform SGPR base + small imm.
__global__ __launch_bounds__(256)
void whprep_kernel(const float* __restrict__ W, _Float16* __restrict__ Wh)
{
    int i = blockIdx.x * 256 + threadIdx.x;      // 9*8*128*8 = 73728
    if (i >= 9 * 8 * COUT * 8) return;
    const int e  = i & 7;
    const int co = (i >> 3) & 127;
    const int tq = (i >> 10) & 7;
    const int kk = i >> 13;
    const int q  = tq & 1;
    const int t  = tq >> 1;
    const int ci = t * 16 + q * 8 + e;
    Wh[i] = (_Float16)W[((size_t)co * CIN + ci) * 9 + kk];
}

// ---------- Prep: x fp32 NCHW -> xh f16 NHWC (plain, no swizzle) ----------
__global__ __launch_bounds__(256)
void xprep_kernel(const float* __restrict__ x, _Float16* __restrict__ xh)
{
    const int tid = threadIdx.x;
    const int w = tid & 127;
    const int h = blockIdx.x * 2 + (tid >> 7);
    const int b = blockIdx.y;
    const float* xp = x + ((size_t)b * CIN * HIN + h) * WIN + w;   // + c*16384
    _Float16* op = xh + ((size_t)(b * 128 + h) * 128 + w) * 64;
    #pragma unroll
    for (int cg = 0; cg < 8; ++cg) {
        f16x8 o;
        #pragma unroll
        for (int j = 0; j < 8; ++j)
            o[j] = (_Float16)xp[(size_t)(cg * 8 + j) * (HIN * WIN)];
        *(f16x8*)(op + cg * 8) = o;
    }
}

// ---------- Conv: A from LDS (pad-72, measured 0 conflicts), B via asm-pipelined ----------
// global loads with counted s_waitcnt vmcnt(N) (AITER pattern: never drain to 0 mid-loop).
// grid (63 row-pairs, 2 px-halves, 32 batch); block 256 = 4 waves (mi row x ni cout-half).
// Wave tile M=64 x N=64 = 2x2 of 32x32; acc = 64 AGPR. B slots: 3 x 8 x b128 regs,
// issued 2 taps ahead; consumed behind vmcnt(16/8/0) + sched_barrier(0) (rule #18).
// ZERO barriers in the K-loop -> no compiler vmcnt(0) drain anywhere near the pipeline.
__global__ __launch_bounds__(256, 2)
void conv_mfma_kernel(const _Float16* __restrict__ xh, const _Float16* __restrict__ Wh,
                      const float* __restrict__ bias, const float* __restrict__ gamma,
                      const float* __restrict__ scale,
                      _Float16* __restrict__ yp, float* __restrict__ stats)
{
    const int tid  = threadIdx.x;
    const int lane = tid & 63;
    const int wave = tid >> 6;
    const int mi   = wave & 1;       // output row 2rp+mi
    const int ni   = wave >> 1;      // cout half (0: 0..63, 1: 64..127)
    const int cl   = lane & 31;      // m-lane (px) for A, n-lane (cout) for B/D
    const int q    = lane >> 5;      // k-half
    const int rp   = blockIdx.x;     // 0..62
    const int half = blockIdx.y;     // px half (0: 0..63, 1: 64..127)
    const int b    = blockIdx.z;

    // [4 input rows][66 px][72 (64 cin + pad8)] f16; row stride 4752; 38016 B -> 2 blocks/CU
    __shared__ __align__(16) _Float16 sx[4 * 4752];

    const char* whb = (const char*)Wh;
    const uint32_t voff = (uint32_t)(q * 2048 + (ni * 64 + cl) * 16);

    f16x8 Bs0[8], Bs1[8], Bs2[8];

#define B_ISSUE(KK, S) \
    asm volatile("global_load_dwordx4 %0, %1, %2 offset:0"   : "=&v"(S[0]) : "v"(voff), "s"(whb + (KK)*16384)); \
    asm volatile("global_load_dwordx4 %0, %1, %2 offset:512" : "=&v"(S[1]) : "v"(voff), "s"(whb + (KK)*16384)); \
    asm volatile("global_load_dwordx4 %0, %1, %2 offset:0"   : "=&v"(S[2]) : "v"(voff), "s"(whb + (KK)*16384 + 4096)); \
    asm volatile("global_load_dwordx4 %0, %1, %2 offset:512" : "=&v"(S[3]) : "v"(voff), "s"(whb + (KK)*16384 + 4096)); \
    asm volatile("global_load_dwordx4 %0, %1, %2 offset:0"   : "=&v"(S[4]) : "v"(voff), "s"(whb + (KK)*16384 + 8192)); \
    asm volatile("global_load_dwordx4 %0, %1, %2 offset:512" : "=&v"(S[5]) : "v"(voff), "s"(whb + (KK)*16384 + 8192)); \
    asm volatile("global_load_dwordx4 %0, %1, %2 offset:0"   : "=&v"(S[6]) : "v"(voff), "s"(whb + (KK)*16384 + 12288)); \
    asm volatile("global_load_dwordx4 %0, %1, %2 offset:512" : "=&v"(S[7]) : "v"(voff), "s"(whb + (KK)*16384 + 12288));

#define WAITVM(N) asm volatile("s_waitcnt vmcnt(" #N ")" ::: "memory")

#define MFMA(A, Bf, C) C = __builtin_amdgcn_mfma_f32_32x32x16_f16(A, Bf, C, 0, 0, 0)

    // ---- issue B taps 0,1 (latency hides under A staging) ----
    B_ISSUE(0, Bs0)
    B_ISSUE(1, Bs1)

    // ---- stage A: wave w stages row 2rp+w, px half*64 .. +65 (pad-72 layout) ----
    {
        const size_t grow = ((size_t)(b * 128 + 2 * rp + wave)) * 8192 + (size_t)half * 64 * 64;
        const int pxl = lane >> 3, cb = lane & 7;
        _Float16* dst = sx + wave * 4752;
        #pragma unroll
        for (int it = 0; it < 8; ++it) {
            const int px = it * 8 + pxl;
            const f16x8 v = *(const f16x8*)(xh + grow + px * 64 + cb * 8);
            *(f16x8*)(dst + px * 72 + cb * 8) = v;
        }
        if (lane < 16) {                       // px 64,65 halo (xh has slack for over-read)
            const int px = 64 + (lane >> 3);
            const f16x8 v = *(const f16x8*)(xh + grow + px * 64 + cb * 8);
            *(f16x8*)(dst + px * 72 + cb * 8) = v;
        }
    }
    __syncthreads();

    f32x16 acc00 = {}, acc01 = {}, acc10 = {}, acc11 = {};

    const _Float16* apb = sx + mi * 4752 + cl * 72 + q * 8;   // + kh*4752 + kw*72 + mt*2304 + t*16

#define TAP(KH, KW, S, WN) { \
    const _Float16* at_ = apb + (KH) * 4752 + (KW) * 72; \
    const f16x8 a00 = *(const f16x8*)(at_);             \
    const f16x8 a01 = *(const f16x8*)(at_ + 16);        \
    const f16x8 a02 = *(const f16x8*)(at_ + 32);        \
    const f16x8 a03 = *(const f16x8*)(at_ + 48);        \
    const f16x8 a10 = *(const f16x8*)(at_ + 2304);      \
    const f16x8 a11 = *(const f16x8*)(at_ + 2304 + 16); \
    const f16x8 a12 = *(const f16x8*)(at_ + 2304 + 32); \
    const f16x8 a13 = *(const f16x8*)(at_ + 2304 + 48); \
    WAITVM(WN); \
    __builtin_amdgcn_sched_barrier(0); \
    MFMA(a00, S[0], acc00); MFMA(a00, S[1], acc01); \
    MFMA(a10, S[0], acc10); MFMA(a10, S[1], acc11); \
    MFMA(a01, S[2], acc00); MFMA(a01, S[3], acc01); \
    MFMA(a11, S[2], acc10); MFMA(a11, S[3], acc11); \
    MFMA(a02, S[4], acc00); MFMA(a02, S[5], acc01); \
    MFMA(a12, S[4], acc10); MFMA(a12, S[5], acc11); \
    MFMA(a03, S[6], acc00); MFMA(a03, S[7], acc01); \
    MFMA(a13, S[6], acc10); MFMA(a13, S[7], acc11); }

    // tap kk consumes slot kk%3; at top of tap kk we issue tap kk+2 into slot (kk+2)%3.
    // outstanding before wait: 24 (kk<=6) -> vmcnt(16); 16 (kk=7) -> vmcnt(8); 8 (kk=8) -> vmcnt(0).
    B_ISSUE(2, Bs2) TAP(0, 0, Bs0, 16)
    B_ISSUE(3, Bs0) TAP(0, 1, Bs1, 16)
    B_ISSUE(4, Bs1) TAP(0, 2, Bs2, 16)
    B_ISSUE(5, Bs2) TAP(1, 0, Bs0, 16)
    B_ISSUE(6, Bs0) TAP(1, 1, Bs1, 16)
    B_ISSUE(7, Bs1) TAP(1, 2, Bs2, 16)
    B_ISSUE(8, Bs2) TAP(2, 0, Bs0, 16)
                    TAP(2, 1, Bs1, 8)
                    TAP(2, 2, Bs2, 0)

#undef TAP
#undef MFMA
#undef WAITVM
#undef B_ISSUE

    f32x16 acc[2][2] = {{acc00, acc01}, {acc10, acc11}};

    // ---- epilogue: bias, stats, horizontal pool ----
    // D layout (32x32): col(cout)=cl, row(px in tile) = (r&3)+4q+8(r>>2); r = ru*4+pl*2+e.
    // wo = half*64 + mt*32 + 8ru + 4q + 2pl + e; invalid only wo>=126 (half=1,mt=1,ru=3,q=1,pl=1).
    float ev[2][2][4][2];   // [nt][mt][ru][pl] horizontal extremum
    float s1[2] = {0.f, 0.f}, s2[2] = {0.f, 0.f};
    bool  useMin[2];
    #pragma unroll
    for (int nt = 0; nt < 2; ++nt) {
        const int co = ni * 64 + nt * 32 + cl;
        const float bv = bias[co];
        useMin[nt] = (gamma[co] * scale[co]) < 0.0f;   // affine slope sign (rstd>0)
        #pragma unroll
        for (int mt = 0; mt < 2; ++mt)
            #pragma unroll
            for (int ru = 0; ru < 4; ++ru)
                #pragma unroll
                for (int pl = 0; pl < 2; ++pl) {
                    const float e0 = acc[mt][nt][ru * 4 + pl * 2 + 0] + bv;
                    const float e1 = acc[mt][nt][ru * 4 + pl * 2 + 1] + bv;
                    const bool bad = (half == 1) && (mt == 1) && (ru == 3) && (q == 1) && (pl == 1);
                    if (!bad) { s1[nt] += e0 + e1; s2[nt] += e0 * e0 + e1 * e1; }
                    ev[nt][mt][ru][pl] = useMin[nt] ? fminf(e0, e1) : fmaxf(e0, e1);
                }
    }

    // stats: reduce over the 32 lanes sharing a 16-cout group-half: xor 1,2,4,8,32
    #pragma unroll
    for (int nt = 0; nt < 2; ++nt) {
        float a1 = s1[nt], a2 = s2[nt];
        a1 += __shfl_xor(a1, 1);  a2 += __shfl_xor(a2, 1);
        a1 += __shfl_xor(a1, 2);  a2 += __shfl_xor(a2, 2);
        a1 += __shfl_xor(a1, 4);  a2 += __shfl_xor(a2, 4);
        a1 += __shfl_xor(a1, 8);  a2 += __shfl_xor(a2, 8);
        a1 += __shfl_xor(a1, 32); a2 += __shfl_xor(a2, 32);
        if ((lane & 15) == 0 && lane < 32) {
            const int g = ni * 4 + nt * 2 + (cl >> 4);
            atomicAdd(&stats[((size_t)b * NG + g) * 2 + 0], a1);
            atomicAdd(&stats[((size_t)b * NG + g) * 2 + 1], a2);
        }
    }

    // vertical combine: mi=1 publishes, mi=0 combines + stores yp
    __syncthreads();               // all K-loop LDS reads done; safe to reuse sx
    _Float16* ex = sx;             // [ (ni*2+nt)*32 + pp ][ cl ] f16, 8KB
    if (mi == 1) {
        #pragma unroll
        for (int nt = 0; nt < 2; ++nt)
            #pragma unroll
            for (int mt = 0; mt < 2; ++mt)
                #pragma unroll
                for (int ru = 0; ru < 4; ++ru)
                    #pragma unroll
                    for (int pl = 0; pl < 2; ++pl) {
                        const int pp = mt * 16 + ru * 4 + q * 2 + pl;
                        ex[((ni * 2 + nt) * 32 + pp) * 32 + cl] = (_Float16)ev[nt][mt][ru][pl];
                    }
    }
    __syncthreads();
    if (mi == 0) {
        #pragma unroll
        for (int nt = 0; nt < 2; ++nt) {
            const int co = ni * 64 + nt * 32 + cl;
            _Float16* ypp = yp + ((size_t)(b * COUT + co) * HP + rp) * 64 + half * 32;
            #pragma unroll
            for (int mt = 0; mt < 2; ++mt)
                #pragma unroll
                for (int ru = 0; ru < 4; ++ru) {
                    const int ppb = mt * 16 + ru * 4 + q * 2;
                    const float r0 = (float)ex[((ni * 2 + nt) * 32 + ppb + 0) * 32 + cl];
                    const float r1 = (float)ex[((ni * 2 + nt) * 32 + ppb + 1) * 32 + cl];
                    const float c0 = useMin[nt] ? fminf(ev[nt][mt][ru][0], r0) : fmaxf(ev[nt][mt][ru][0], r0);
                    const float c1 = useMin[nt] ? fminf(ev[nt][mt][ru][1], r1) : fmaxf(ev[nt][mt][ru][1], r1);
                    *(f16x2*)(ypp + ppb) = (f16x2){(_Float16)c0, (_Float16)c1};
                }
        }
    }
}

// ---------- GroupNorm affine + clamp on pre-pooled extrema ----------
__global__ __launch_bounds__(256)
void gn_pool_kernel(const _Float16* __restrict__ yp, const float* __restrict__ stats,
                    const float* __restrict__ gamma, const float* __restrict__ beta,
                    const float* __restrict__ scale, float* __restrict__ out)
{
    const int bc = blockIdx.x;           // b*COUT + c
    const int c  = bc & 127;
    const int b  = bc >> 7;
    const int g  = c >> 4;

    const float s1 = stats[((size_t)b * NG + g) * 2 + 0];
    const float s2 = stats[((size_t)b * NG + g) * 2 + 1];
    constexpr float inv = 1.0f / (float)((COUT / NG) * HO * WO);
    const float mean = s1 * inv;
    const float var  = fmaf(-mean, mean, s2 * inv);
    const float rstd = rsqrtf(var + EPS);
    const float sc   = scale[c];
    const float a    = rstd * gamma[c] * sc;
    const float bb   = fmaf(-mean, rstd * gamma[c], beta[c]) * sc;

    const _Float16* ypp = yp + (size_t)bc * HP * 64;
    float* op = out + (size_t)bc * HP * WP;
    #pragma unroll
    for (int it = 0; it < 8; ++it) {
        const int j = it * 256 + threadIdx.x;     // pair index, 63 rows x 32 pairs = 2016
        if (j < 2016) {
            const int wp = (j & 31) * 2;
            const int hp = j >> 5;
            const f16x2 v = *(const f16x2*)(ypp + hp * 64 + wp);
            float m0 = fmaf((float)v[0], a, bb);
            m0 = fminf(fmaxf(m0, 0.0f), 1.0f);
            op[hp * WP + wp] = m0;
            if (wp + 1 < WP) {
                float m1 = fmaf((float)v[1], a, bb);
                m1 = fminf(fmaxf(m1, 0.0f), 1.0f);
                op[hp * WP + wp + 1] = m1;
            }
        }
    }
}

extern "C" void kernel_launch(void* const* d_in, const int* in_sizes, int n_in,
                              void* d_out, int out_size, void* d_ws, size_t ws_size,
                              hipStream_t stream)
{
    const float* x     = (const float*)d_in[0];
    const float* W     = (const float*)d_in[1];
    const float* bias  = (const float*)d_in[2];
    const float* scale = (const float*)d_in[3];
    const float* gamma = (const float*)d_in[4];
    const float* beta  = (const float*)d_in[5];

    float*    stats = (float*)d_ws;
    _Float16* Wh    = (_Float16*)((char*)d_ws + 4096);
    _Float16* xh    = (_Float16*)((char*)d_ws + 151552);
    _Float16* yp    = (_Float16*)((char*)d_ws + 67264512);
    float*    out   = (float*)d_out;

    hipMemsetAsync(stats, 0, B_ * NG * 2 * sizeof(float), stream);

    whprep_kernel<<<(9 * 8 * COUT * 8 + 255) / 256, 256, 0, stream>>>(W, Wh);
    xprep_kernel<<<dim3(64, B_), 256, 0, stream>>>(x, xh);
    conv_mfma_kernel<<<dim3(63, 2, B_), 256, 0, stream>>>(xh, Wh, bias, gamma, scale, yp, stats);
    gn_pool_kernel<<<B_ * COUT, 256, 0, stream>>>(yp, stats, gamma, beta, scale, out);
}

// Round 7
// 380.881 us; speedup vs baseline: 1.1913x; 1.1913x over previous
//
#include <hip/hip_runtime.h>
#include <hip/hip_bf16.h>

// Problem constants
constexpr int B_   = 32;
constexpr int CIN  = 64;
constexpr int HIN  = 128;
constexpr int WIN  = 128;
constexpr int COUT = 128;
constexpr int HO   = 126;
constexpr int WO   = 126;
constexpr int HP   = 63;
constexpr int WP   = 63;
constexpr int NG   = 8;
constexpr float EPS = 1e-5f;

typedef _Float16 f16x8 __attribute__((ext_vector_type(8)));
typedef _Float16 f16x2 __attribute__((ext_vector_type(2)));
typedef float    f32x16 __attribute__((ext_vector_type(16)));

// ws layout (bytes):
//   stats @ 0        : 512 floats (pad to 4096)
//   Wh    @ 4096     : 9*128*64 f16 = 147456                      (ends 151552)
//   xh    @ 151552   : 32*128*[8 cgrp][128 px][8] f16 = 64 MB     (ends 67260416)
//   yp    @ 67264512 : 32*128*63*64 f16 = 33 MB (padded wp-stride 64)

// ---------- Prep: W (OIHW fp32) -> Wh[kh*kw][cout][cin] f16 ----------
__global__ __launch_bounds__(256)
void whprep_kernel(const float* __restrict__ W, _Float16* __restrict__ Wh)
{
    int i = blockIdx.x * 256 + threadIdx.x;
    if (i >= 9 * COUT * CIN) return;
    int c  = i & 63;
    int co = (i >> 6) & 127;
    int kk = i >> 13;
    Wh[i] = (_Float16)W[((size_t)co * CIN + c) * 9 + kk];
}

// ---------- Prep: x fp32 NCHW -> xh f16 chunked [b][h][cg][px][8] ----------
// KEY FIX vs rounds 0-6: store addr = cg*1024 + w*8 -> lane-contiguous 16B stores
// (fully coalesced, 2KB/segment). Old layout wrote 16B/lane at 128B stride =
// 8 partial writes per cache line -> suspected source of the constant ~230us tail.
__global__ __launch_bounds__(256)
void xprep_kernel(const float* __restrict__ x, _Float16* __restrict__ xh)
{
    const int tid = threadIdx.x;
    const int w = tid & 127;
    const int h = blockIdx.x * 2 + (tid >> 7);
    const int b = blockIdx.y;
    const float* xp = x + ((size_t)b * CIN * HIN + h) * WIN + w;   // + c*16384
    _Float16* op = xh + (size_t)(b * 128 + h) * 8192;
    #pragma unroll
    for (int cg = 0; cg < 8; ++cg) {
        f16x8 o;
        #pragma unroll
        for (int j = 0; j < 8; ++j)
            o[j] = (_Float16)xp[(size_t)(cg * 8 + j) * (HIN * WIN)];   // coalesced 512B/seg
        *(f16x8*)(op + cg * 1024 + w * 8) = o;                         // coalesced 2KB/seg
    }
}

// ---------- Conv (implicit GEMM, 32x32x16 MFMA) + bias + stats + full 2x2 pool ----------
// EXACT round-1 structure (measured 160us, MfmaUtil 20%, 0 conflicts) -- only the
// staging read addresses changed for the chunked xh layout.
// grid (63 row-pairs, 32 batch); block 256 = 4 waves.
// wave = (mi = wave&1 -> output row 2rp+mi, ni = wave>>1 -> cout half).
// Wave tile: M=128 px (full row) x N=64 couts as 4x2 tiles of 32x32; K = 576.
constexpr int ROWSTRIDE = 9360;   // 130 px * 72 (64 cin + pad8) f16 elems per staged row

__global__ __launch_bounds__(256, 2)
void conv_mfma_kernel(const _Float16* __restrict__ xh, const _Float16* __restrict__ Wh,
                      const float* __restrict__ bias, const float* __restrict__ gamma,
                      const float* __restrict__ scale,
                      _Float16* __restrict__ yp, float* __restrict__ stats)
{
    const int tid  = threadIdx.x;
    const int lane = tid & 63;
    const int wave = tid >> 6;
    const int mi   = wave & 1;
    const int ni   = wave >> 1;
    const int cl   = lane & 31;      // m-lane (px) for A, n-lane (cout) for B/D
    const int q    = lane >> 5;      // k-half
    const int rp   = blockIdx.x;     // 0..62
    const int b    = blockIdx.y;

    // [4 input rows][130 px][72 (64 cin + pad8)] f16 ; 74,880 B -> 2 blocks/CU
    __shared__ _Float16 sx[4 * ROWSTRIDE];

    // ---- stage: wave w stages full input row 2rp+w (128 px; px 128/129 left
    // uninitialized -> flows only into masked outputs wo>=126, as in round 1) ----
    {
        const size_t grow = (size_t)(b * 128 + 2 * rp + wave) * 8192;
        const int pxl = lane >> 3, cb = lane & 7;
        _Float16* dst = sx + wave * ROWSTRIDE;
        #pragma unroll
        for (int it = 0; it < 16; ++it) {
            const int px = it * 8 + pxl;
            const f16x8 v = *(const f16x8*)(xh + grow + cb * 1024 + px * 8);  // chunked layout
            *(f16x8*)(dst + px * 72 + cb * 8) = v;
        }
    }
    __syncthreads();

    f32x16 acc[4][2] = {};

    const _Float16* apbase = sx + mi * ROWSTRIDE + cl * 72 + q * 8;  // + kh*RS + (kw+mt*32)*72 + t*16
    const _Float16* bpbase = Wh + (ni * 64 + cl) * 64 + q * 8;       // + kk*8192 + nt*2048 + t*16

    #pragma unroll
    for (int kk = 0; kk < 9; ++kk) {
        const int kh = kk / 3, kw = kk - kh * 3;
        const _Float16* ap = apbase + kh * ROWSTRIDE + kw * 72;
        const _Float16* bp = bpbase + kk * 8192;
        #pragma unroll
        for (int t = 0; t < 4; ++t) {
            const f16x8 b0 = *(const f16x8*)(bp + t * 16);
            const f16x8 b1 = *(const f16x8*)(bp + 2048 + t * 16);
            #pragma unroll
            for (int mt = 0; mt < 4; ++mt) {
                const f16x8 a = *(const f16x8*)(ap + mt * 2304 + t * 16);
                acc[mt][0] = __builtin_amdgcn_mfma_f32_32x32x16_f16(a, b0, acc[mt][0], 0, 0, 0);
                acc[mt][1] = __builtin_amdgcn_mfma_f32_32x32x16_f16(a, b1, acc[mt][1], 0, 0, 0);
            }
        }
    }

    // ---- epilogue: bias, stats, horizontal pool ----
    // D layout (32x32): col(cout)=cl, row(px)= (r&3)+4q+8(r>>2); r = ru*4+pl*2+e.
    // wo = mt*32 + 8ru + 4q + 2pl + e; invalid only wo>=126 (mt==3,ru==3,q==1,pl==1).
    float ev[2][4][4][2];   // [nt][mt][ru][pl] horizontal extremum
    float s1[2] = {0.f, 0.f}, s2[2] = {0.f, 0.f};
    bool  useMin[2];
    #pragma unroll
    for (int nt = 0; nt < 2; ++nt) {
        const int co = ni * 64 + nt * 32 + cl;
        const float bv = bias[co];
        useMin[nt] = (gamma[co] * scale[co]) < 0.0f;   // affine slope sign (rstd>0)
        #pragma unroll
        for (int mt = 0; mt < 4; ++mt)
            #pragma unroll
            for (int ru = 0; ru < 4; ++ru)
                #pragma unroll
                for (int pl = 0; pl < 2; ++pl) {
                    const float e0 = acc[mt][nt][ru * 4 + pl * 2 + 0] + bv;
                    const float e1 = acc[mt][nt][ru * 4 + pl * 2 + 1] + bv;
                    const bool bad = (mt == 3) && (ru == 3) && (q == 1) && (pl == 1);
                    if (!bad) { s1[nt] += e0 + e1; s2[nt] += e0 * e0 + e1 * e1; }
                    ev[nt][mt][ru][pl] = useMin[nt] ? fminf(e0, e1) : fmaxf(e0, e1);
                }
    }

    // stats: reduce over the 32 lanes sharing a 16-cout group-half: xor 1,2,4,8,32
    #pragma unroll
    for (int nt = 0; nt < 2; ++nt) {
        float a1 = s1[nt], a2 = s2[nt];
        a1 += __shfl_xor(a1, 1);  a2 += __shfl_xor(a2, 1);
        a1 += __shfl_xor(a1, 2);  a2 += __shfl_xor(a2, 2);
        a1 += __shfl_xor(a1, 4);  a2 += __shfl_xor(a2, 4);
        a1 += __shfl_xor(a1, 8);  a2 += __shfl_xor(a2, 8);
        a1 += __shfl_xor(a1, 32); a2 += __shfl_xor(a2, 32);
        if ((lane & 15) == 0 && lane < 32) {
            const int g = ni * 4 + nt * 2 + (cl >> 4);
            atomicAdd(&stats[((size_t)b * NG + g) * 2 + 0], a1);
            atomicAdd(&stats[((size_t)b * NG + g) * 2 + 1], a2);
        }
    }

    // vertical combine: mi=1 publishes, mi=0 combines + stores yp
    __syncthreads();               // all K-loop LDS reads done; safe to reuse sx
    _Float16* ex = sx;             // [ (ni*2+nt)*64 + pp ][ cl ] f16, 16KB
    if (mi == 1) {
        #pragma unroll
        for (int nt = 0; nt < 2; ++nt)
            #pragma unroll
            for (int mt = 0; mt < 4; ++mt)
                #pragma unroll
                for (int ru = 0; ru < 4; ++ru)
                    #pragma unroll
                    for (int pl = 0; pl < 2; ++pl) {
                        const int pp = mt * 16 + ru * 4 + q * 2 + pl;
                        ex[((ni * 2 + nt) * 64 + pp) * 32 + cl] = (_Float16)ev[nt][mt][ru][pl];
                    }
    }
    __syncthreads();
    if (mi == 0) {
        #pragma unroll
        for (int nt = 0; nt < 2; ++nt) {
            const int co = ni * 64 + nt * 32 + cl;
            _Float16* ypp = yp + ((size_t)(b * COUT + co) * HP + rp) * 64;
            #pragma unroll
            for (int mt = 0; mt < 4; ++mt)
                #pragma unroll
                for (int ru = 0; ru < 4; ++ru) {
                    const int ppb = mt * 16 + ru * 4 + q * 2;
                    const float r0 = (float)ex[((ni * 2 + nt) * 64 + ppb + 0) * 32 + cl];
                    const float r1 = (float)ex[((ni * 2 + nt) * 64 + ppb + 1) * 32 + cl];
                    const float c0 = useMin[nt] ? fminf(ev[nt][mt][ru][0], r0) : fmaxf(ev[nt][mt][ru][0], r0);
                    const float c1 = useMin[nt] ? fminf(ev[nt][mt][ru][1], r1) : fmaxf(ev[nt][mt][ru][1], r1);
                    *(f16x2*)(ypp + ppb) = (f16x2){(_Float16)c0, (_Float16)c1};
                }
        }
    }
}

// ---------- GroupNorm affine + clamp on pre-pooled extrema ----------
// One block per (b,c) plane; one output ROW per wave-iteration:
// f16 read and f32 write both lane-contiguous (fully coalesced).
__global__ __launch_bounds__(256)
void gn_pool_kernel(const _Float16* __restrict__ yp, const float* __restrict__ stats,
                    const float* __restrict__ gamma, const float* __restrict__ beta,
                    const float* __restrict__ scale, float* __restrict__ out)
{
    const int bc = blockIdx.x;           // b*COUT + c
    const int c  = bc & 127;
    const int b  = bc >> 7;
    const int g  = c >> 4;

    const float s1 = stats[((size_t)b * NG + g) * 2 + 0];
    const float s2 = stats[((size_t)b * NG + g) * 2 + 1];
    constexpr float inv = 1.0f / (float)((COUT / NG) * HO * WO);
    const float mean = s1 * inv;
    const float var  = fmaf(-mean, mean, s2 * inv);
    const float rstd = rsqrtf(var + EPS);
    const float sc   = scale[c];
    const float a    = rstd * gamma[c] * sc;
    const float bb   = fmaf(-mean, rstd * gamma[c], beta[c]) * sc;

    const int wave = threadIdx.x >> 6;
    const int lane = threadIdx.x & 63;
    const _Float16* ypp = yp + (size_t)bc * HP * 64;
    float* op = out + (size_t)bc * HP * WP;
    if (lane < WP) {
        #pragma unroll
        for (int it = 0; it < 16; ++it) {
            const int hp = it * 4 + wave;
            if (hp < HP) {
                const float v = (float)ypp[hp * 64 + lane];
                float m = fmaf(v, a, bb);
                m = fminf(fmaxf(m, 0.0f), 1.0f);
                op[hp * WP + lane] = m;
            }
        }
    }
}

extern "C" void kernel_launch(void* const* d_in, const int* in_sizes, int n_in,
                              void* d_out, int out_size, void* d_ws, size_t ws_size,
                              hipStream_t stream)
{
    const float* x     = (const float*)d_in[0];
    const float* W     = (const float*)d_in[1];
    const float* bias  = (const float*)d_in[2];
    const float* scale = (const float*)d_in[3];
    const float* gamma = (const float*)d_in[4];
    const float* beta  = (const float*)d_in[5];

    float*    stats = (float*)d_ws;
    _Float16* Wh    = (_Float16*)((char*)d_ws + 4096);
    _Float16* xh    = (_Float16*)((char*)d_ws + 151552);
    _Float16* yp    = (_Float16*)((char*)d_ws + 67264512);
    float*    out   = (float*)d_out;

    hipMemsetAsync(stats, 0, B_ * NG * 2 * sizeof(float), stream);

    whprep_kernel<<<(9 * COUT * CIN + 255) / 256, 256, 0, stream>>>(W, Wh);
    xprep_kernel<<<dim3(64, B_), 256, 0, stream>>>(x, xh);
    conv_mfma_kernel<<<dim3(63, B_), 256, 0, stream>>>(xh, Wh, bias, gamma, scale, yp, stats);
    gn_pool_kernel<<<B_ * COUT, 256, 0, stream>>>(yp, stats, gamma, beta, scale, out);
}